// Round 1
// baseline (531.827 us; speedup 1.0000x reference)
//
#include <hip/hip_runtime.h>
#include <cstdint>
#include <cstddef>

typedef short s8vec __attribute__((ext_vector_type(8)));     // 8 bf16 (4 VGPRs)
typedef float f16acc __attribute__((ext_vector_type(16)));   // 16 fp32 acc

#define C_DIM 256
#define M_DIM 16384
#define BATCH 8
#define KSPLIT 32
#define KCHUNK 512
#define BK 64
#define LDSP 72   // padded LDS pitch in bf16 elems (144 B, 16B-aligned, conflict-breaking)

static __device__ __forceinline__ unsigned short f2bf(float f) {
    union { float f; unsigned u; } v; v.f = f;
    unsigned r = v.u + 0x7fffu + ((v.u >> 16) & 1u);  // round-to-nearest-even
    return (unsigned short)(r >> 16);
}
static __device__ __forceinline__ float bf2f(unsigned short h) {
    union { unsigned u; float f; } v; v.u = ((unsigned)h) << 16;
    return v.f;
}

// ---------------------------------------------------------------------------
// cov partial: covraw[b] += Xchunk @ Xchunk^T  (bf16 MFMA, fp32 atomics)
// also accumulates channel sums for the mean.
// grid (KSPLIT, BATCH), 512 threads (8 waves: 2x4, each wave 128x64 of 256x256)
// ---------------------------------------------------------------------------
__global__ __launch_bounds__(512, 2)
void cov_kernel(const float* __restrict__ x, float* __restrict__ covraw,
                float* __restrict__ sums)
{
    __shared__ unsigned short Xs[C_DIM][LDSP];
    const int b   = blockIdx.y;
    const int kc  = blockIdx.x;
    const int tid = threadIdx.x;
    const int lane = tid & 63;
    const int wave = tid >> 6;     // 0..7
    const int wr = wave >> 2;      // 0..1 -> row * 128
    const int wc = wave & 3;       // 0..3 -> col * 64
    const int half = lane >> 5;    // 0/1
    const int l31  = lane & 31;

    const float* xb = x + (size_t)b * C_DIM * M_DIM + (size_t)kc * KCHUNK;

    f16acc acc[4][2] = {};
    float rowsum[8] = {0,0,0,0,0,0,0,0};
    const int r0 = tid >> 4;         // 0..31
    const int c0 = (tid & 15) * 4;   // 0..60

    for (int kt = 0; kt < KCHUNK / BK; ++kt) {
        float4 v[8];
        const float* src = xb + (size_t)r0 * M_DIM + kt * BK + c0;
        #pragma unroll
        for (int i = 0; i < 8; ++i)
            v[i] = *(const float4*)(src + (size_t)(32 * i) * M_DIM);
        __syncthreads();
        #pragma unroll
        for (int i = 0; i < 8; ++i) {
            rowsum[i] += v[i].x + v[i].y + v[i].z + v[i].w;
            ushort4 p;
            p.x = f2bf(v[i].x); p.y = f2bf(v[i].y);
            p.z = f2bf(v[i].z); p.w = f2bf(v[i].w);
            *(ushort4*)&Xs[r0 + 32 * i][c0] = p;
        }
        __syncthreads();
        #pragma unroll
        for (int ks = 0; ks < 4; ++ks) {
            const int k0 = ks * 16 + half * 8;
            s8vec af[4], bfr[2];
            #pragma unroll
            for (int i = 0; i < 4; ++i)
                af[i] = *(const s8vec*)&Xs[wr * 128 + i * 32 + l31][k0];
            #pragma unroll
            for (int j = 0; j < 2; ++j)
                bfr[j] = *(const s8vec*)&Xs[wc * 64 + j * 32 + l31][k0];
            #pragma unroll
            for (int i = 0; i < 4; ++i)
                #pragma unroll
                for (int j = 0; j < 2; ++j)
                    acc[i][j] = __builtin_amdgcn_mfma_f32_32x32x16_bf16(
                        af[i], bfr[j], acc[i][j], 0, 0, 0);
        }
    }
    // channel sums: 16 consecutive lanes share one row
    #pragma unroll
    for (int i = 0; i < 8; ++i) {
        float s = rowsum[i];
        s += __shfl_down(s, 8, 16);
        s += __shfl_down(s, 4, 16);
        s += __shfl_down(s, 2, 16);
        s += __shfl_down(s, 1, 16);
        if ((lane & 15) == 0)
            atomicAdd(&sums[b * C_DIM + r0 + 32 * i], s);
    }
    float* covb = covraw + (size_t)b * C_DIM * C_DIM;
    #pragma unroll
    for (int i = 0; i < 4; ++i) {
        const int rb = wr * 128 + i * 32 + 4 * half;
        #pragma unroll
        for (int j = 0; j < 2; ++j) {
            const int cb = wc * 64 + j * 32 + l31;
            #pragma unroll
            for (int r = 0; r < 16; ++r) {
                const int row = rb + (r & 3) + 8 * (r >> 2);
                atomicAdd(&covb[row * C_DIM + cb], acc[i][j][r]);
            }
        }
    }
}

// ---------------------------------------------------------------------------
// finalize: cov = covraw/M - mu mu^T ; normA = ||cov||_F ; Y0 = cov/normA (bf16);
// Z0 = I. grid BATCH x 1024 threads.
// ---------------------------------------------------------------------------
__global__ __launch_bounds__(1024)
void finalize_cov(const float* __restrict__ covraw, const float* __restrict__ sums,
                  float* __restrict__ normA_g, unsigned short* __restrict__ Y0,
                  unsigned short* __restrict__ Z0)
{
    const int b = blockIdx.x;
    const int tid = threadIdx.x;
    const float invM = 1.0f / (float)M_DIM;
    const float* cb = covraw + (size_t)b * 65536;
    const float* sb = sums + b * 256;
    float vals[64];
    float ss = 0.0f;
    #pragma unroll
    for (int i = 0; i < 64; ++i) {
        const int e = tid + i * 1024;
        const int r = e >> 8, c = e & 255;
        float v = cb[e] * invM - (sb[r] * invM) * (sb[c] * invM);
        vals[i] = v;
        ss += v * v;
    }
    __shared__ float red[16];
    __shared__ float sh_inv;
    float s = ss;
    #pragma unroll
    for (int off = 32; off; off >>= 1) s += __shfl_down(s, off, 64);
    if ((tid & 63) == 0) red[tid >> 6] = s;
    __syncthreads();
    if (tid == 0) {
        float t = 0.0f;
        #pragma unroll
        for (int i = 0; i < 16; ++i) t += red[i];
        float na = sqrtf(t);
        normA_g[b] = na;
        sh_inv = 1.0f / na;
    }
    __syncthreads();
    const float inv = sh_inv;
    unsigned short* yb = Y0 + (size_t)b * 65536;
    unsigned short* zb = Z0 + (size_t)b * 65536;
    #pragma unroll
    for (int i = 0; i < 64; ++i) {
        const int e = tid + i * 1024;
        const int r = e >> 8, c = e & 255;
        yb[e] = f2bf(vals[i] * inv);
        zb[e] = (r == c) ? (unsigned short)0x3f80 : (unsigned short)0;
    }
}

// ---------------------------------------------------------------------------
// NS stage: C = c0*I + c1*(A @ B). All iterates symmetric => read B row-major
// along k (NT-gemm): C[i][j] = c0*d_ij + c1 * sum_k A[i][k]*B[j][k].
// grid (4 tiles of 128x128, BATCH, nprod), 256 threads (4 waves 2x2, 64x64 each)
// ---------------------------------------------------------------------------
__global__ __launch_bounds__(256, 2)
void ns_stage(const unsigned short* __restrict__ A0, const unsigned short* __restrict__ B0,
              unsigned short* __restrict__ C0,
              const unsigned short* __restrict__ A1, const unsigned short* __restrict__ B1,
              unsigned short* __restrict__ C1,
              float c0, float c1)
{
    __shared__ unsigned short As[128][LDSP];
    __shared__ unsigned short Bs[128][LDSP];
    const int b = blockIdx.y;
    const int trow = blockIdx.x >> 1, tcol = blockIdx.x & 1;
    const unsigned short* A = (blockIdx.z ? A1 : A0) + (size_t)b * 65536;
    const unsigned short* B = (blockIdx.z ? B1 : B0) + (size_t)b * 65536;
    unsigned short* Cp = (blockIdx.z ? C1 : C0) + (size_t)b * 65536;

    const int tid = threadIdx.x;
    const int lane = tid & 63, wave = tid >> 6;
    const int wr = wave >> 1, wc = wave & 1;
    const int half = lane >> 5, l31 = lane & 31;

    f16acc acc[2][2] = {};

    const int sr = tid >> 3;        // 0..31
    const int sc = (tid & 7) * 8;   // 0..56
    for (int kt = 0; kt < 4; ++kt) {
        const int kb = kt * BK;
        uint4 va[4], vb[4];
        #pragma unroll
        for (int i = 0; i < 4; ++i) {
            va[i] = *(const uint4*)(A + (size_t)(trow * 128 + sr + 32 * i) * 256 + kb + sc);
            vb[i] = *(const uint4*)(B + (size_t)(tcol * 128 + sr + 32 * i) * 256 + kb + sc);
        }
        __syncthreads();
        #pragma unroll
        for (int i = 0; i < 4; ++i) {
            *(uint4*)&As[sr + 32 * i][sc] = va[i];
            *(uint4*)&Bs[sr + 32 * i][sc] = vb[i];
        }
        __syncthreads();
        #pragma unroll
        for (int ks = 0; ks < 4; ++ks) {
            const int k0 = ks * 16 + half * 8;
            s8vec af[2], bfr[2];
            af[0]  = *(const s8vec*)&As[wr * 64 + l31][k0];
            af[1]  = *(const s8vec*)&As[wr * 64 + 32 + l31][k0];
            bfr[0] = *(const s8vec*)&Bs[wc * 64 + l31][k0];
            bfr[1] = *(const s8vec*)&Bs[wc * 64 + 32 + l31][k0];
            #pragma unroll
            for (int i = 0; i < 2; ++i)
                #pragma unroll
                for (int j = 0; j < 2; ++j)
                    acc[i][j] = __builtin_amdgcn_mfma_f32_32x32x16_bf16(
                        af[i], bfr[j], acc[i][j], 0, 0, 0);
        }
    }
    #pragma unroll
    for (int i = 0; i < 2; ++i) {
        const int rb = trow * 128 + wr * 64 + i * 32 + 4 * half;
        #pragma unroll
        for (int j = 0; j < 2; ++j) {
            const int cb = tcol * 128 + wc * 64 + j * 32 + l31;
            #pragma unroll
            for (int r = 0; r < 16; ++r) {
                const int row = rb + (r & 3) + 8 * (r >> 2);
                float v = c1 * acc[i][j][r] + ((row == cb) ? c0 : 0.0f);
                Cp[row * 256 + cb] = f2bf(v);
            }
        }
    }
}

// ---------------------------------------------------------------------------
// gating: y = rowmean(Z)/sqrt(normA); h = relu(y@w1^T+b1); g = sigmoid(h@w2^T+b2)
// grid BATCH x 256 threads
// ---------------------------------------------------------------------------
__global__ __launch_bounds__(256)
void gating_kernel(const unsigned short* __restrict__ Zfin, const float* __restrict__ normA_g,
                   const float* __restrict__ w1, const float* __restrict__ b1,
                   const float* __restrict__ w2, const float* __restrict__ b2,
                   float* __restrict__ g)
{
    const int b = blockIdx.x;
    const int tid = threadIdx.x;
    __shared__ float sy[256];
    __shared__ float sh[32];
    const unsigned short* zr = Zfin + (size_t)b * 65536 + (size_t)tid * 256;
    float s = 0.0f;
    #pragma unroll
    for (int i = 0; i < 32; ++i) {
        uint4 v = *(const uint4*)(zr + i * 8);
        const unsigned short* p = (const unsigned short*)&v;
        #pragma unroll
        for (int j = 0; j < 8; ++j) s += bf2f(p[j]);
    }
    const float scale = (1.0f / 256.0f) / sqrtf(normA_g[b]);
    sy[tid] = s * scale;
    __syncthreads();
    if (tid < 32) {
        float hh = b1[tid];
        const float* w1r = w1 + tid * 256;
        for (int c = 0; c < 256; ++c) hh += w1r[c] * sy[c];
        sh[tid] = hh > 0.0f ? hh : 0.0f;
    }
    __syncthreads();
    float z = b2[tid];
    const float* w2r = w2 + tid * 32;
    #pragma unroll
    for (int j = 0; j < 32; ++j) z += w2r[j] * sh[j];
    g[b * 256 + tid] = 1.0f / (1.0f + expf(-z));
}

// ---------------------------------------------------------------------------
// scale: out = x * g[b,c]; one uniform g per 1024-float4 block chunk
// ---------------------------------------------------------------------------
__global__ __launch_bounds__(256)
void scale_kernel(const float* __restrict__ x, const float* __restrict__ g,
                  float* __restrict__ out)
{
    const float4* x4 = (const float4*)x;
    float4* o4 = (float4*)out;
    #pragma unroll
    for (int it = 0; it < 4; ++it) {
        size_t i = (size_t)blockIdx.x * 1024 + it * 256 + threadIdx.x;
        float gg = g[i >> 12];
        float4 v = x4[i];
        float4 r;
        r.x = v.x * gg; r.y = v.y * gg; r.z = v.z * gg; r.w = v.w * gg;
        o4[i] = r;
    }
}

extern "C" void kernel_launch(void* const* d_in, const int* in_sizes, int n_in,
                              void* d_out, int out_size, void* d_ws, size_t ws_size,
                              hipStream_t stream)
{
    const float* x  = (const float*)d_in[0];
    const float* w1 = (const float*)d_in[1];
    const float* b1 = (const float*)d_in[2];
    const float* w2 = (const float*)d_in[3];
    const float* b2 = (const float*)d_in[4];
    float* out = (float*)d_out;

    char* ws = (char*)d_ws;
    float* covraw = (float*)ws;                        // 2 MB fp32
    float* sums   = (float*)(ws + 2097152);            // 8 KB
    float* normA  = (float*)(ws + 2105344);            // 32 B
    float* g      = (float*)(ws + 2106368);            // 8 KB
    unsigned short* Ybuf[2] = {(unsigned short*)(ws + 4194304),
                               (unsigned short*)(ws + 5242880)};
    unsigned short* Zbuf[2] = {(unsigned short*)(ws + 6291456),
                               (unsigned short*)(ws + 7340032)};
    unsigned short* T = (unsigned short*)(ws + 8388608);  // total 9 MB

    hipMemsetAsync(covraw, 0, 2105344, stream);  // covraw + sums

    cov_kernel<<<dim3(KSPLIT, BATCH), 512, 0, stream>>>(x, covraw, sums);
    finalize_cov<<<BATCH, 1024, 0, stream>>>(covraw, sums, normA, Ybuf[0], Zbuf[0]);

    int cur = 0;
    for (int it = 0; it < 5; ++it) {
        // T = 1.5 I - 0.5 * Z @ Y
        ns_stage<<<dim3(4, BATCH, 1), 256, 0, stream>>>(
            Zbuf[cur], Ybuf[cur], T, Zbuf[cur], Ybuf[cur], T, 1.5f, -0.5f);
        // Ynew = Y @ T ; Znew = T @ Z
        ns_stage<<<dim3(4, BATCH, 2), 256, 0, stream>>>(
            Ybuf[cur], T, Ybuf[1 - cur], T, Zbuf[cur], Zbuf[1 - cur], 0.0f, 1.0f);
        cur ^= 1;
    }
    gating_kernel<<<BATCH, 256, 0, stream>>>(Zbuf[cur], normA, w1, b1, w2, b2, g);
    scale_kernel<<<8192, 256, 0, stream>>>(x, g, out);
}

// Round 2
// 447.737 us; speedup vs baseline: 1.1878x; 1.1878x over previous
//
#include <hip/hip_runtime.h>
#include <cstdint>
#include <cstddef>

typedef short s8vec __attribute__((ext_vector_type(8)));     // 8 bf16 (4 VGPRs)
typedef float f16acc __attribute__((ext_vector_type(16)));   // 16 fp32 acc

#define C_DIM 256
#define M_DIM 16384
#define BATCH 8
#define KSPLIT 32
#define KCHUNK 512
#define BK 64
#define LDSP 72   // padded LDS pitch in bf16 elems (144 B; round-1 measured 0 bank conflicts)

static __device__ __forceinline__ unsigned short f2bf(float f) {
    union { float f; unsigned u; } v; v.f = f;
    unsigned r = v.u + 0x7fffu + ((v.u >> 16) & 1u);  // round-to-nearest-even
    return (unsigned short)(r >> 16);
}
static __device__ __forceinline__ float bf2f(unsigned short h) {
    union { unsigned u; float f; } v; v.u = ((unsigned)h) << 16;
    return v.f;
}

// ---------------------------------------------------------------------------
// cov partial: covraw[b] += Xchunk @ Xchunk^T  (bf16 MFMA, fp32 atomics)
// 1024 threads = 16 waves in a 4x4 tiling (64x64 out per wave, 2x2 32x32 accs).
// Register prefetch: kt+1 global loads issued before kt's MFMA phase.
// grid (KSPLIT, BATCH)
// ---------------------------------------------------------------------------
__global__ __launch_bounds__(1024, 1)
void cov_kernel(const float* __restrict__ x, float* __restrict__ covraw,
                float* __restrict__ sums)
{
    __shared__ unsigned short Xs[C_DIM][LDSP];   // 36 KB
    const int b   = blockIdx.y;
    const int kc  = blockIdx.x;
    const int tid = threadIdx.x;
    const int lane = tid & 63;
    const int wave = tid >> 6;     // 0..15
    const int wr = wave >> 2;      // 0..3 -> row * 64
    const int wc = wave & 3;       // 0..3 -> col * 64
    const int half = lane >> 5;    // 0/1
    const int l31  = lane & 31;

    const float* xb = x + (size_t)b * C_DIM * M_DIM + (size_t)kc * KCHUNK;

    f16acc acc[2][2] = {};
    float rowsum[4] = {0, 0, 0, 0};
    const int r0 = tid >> 4;         // 0..63
    const int c0 = (tid & 15) * 4;   // 0..60

    // prologue: load kt=0
    float4 v[4];
    {
        const float* src = xb + (size_t)r0 * M_DIM + c0;
        #pragma unroll
        for (int i = 0; i < 4; ++i)
            v[i] = *(const float4*)(src + (size_t)(64 * i) * M_DIM);
    }

    for (int kt = 0; kt < KCHUNK / BK; ++kt) {
        __syncthreads();   // LDS consumers of previous kt done
        #pragma unroll
        for (int i = 0; i < 4; ++i) {
            rowsum[i] += v[i].x + v[i].y + v[i].z + v[i].w;
            ushort4 p;
            p.x = f2bf(v[i].x); p.y = f2bf(v[i].y);
            p.z = f2bf(v[i].z); p.w = f2bf(v[i].w);
            *(ushort4*)&Xs[r0 + 64 * i][c0] = p;
        }
        // issue next tile's loads now; consumed at next iteration's store phase
        if (kt < KCHUNK / BK - 1) {
            const float* src = xb + (size_t)r0 * M_DIM + (kt + 1) * BK + c0;
            #pragma unroll
            for (int i = 0; i < 4; ++i)
                v[i] = *(const float4*)(src + (size_t)(64 * i) * M_DIM);
        }
        __syncthreads();
        #pragma unroll
        for (int ks = 0; ks < 4; ++ks) {
            const int k0 = ks * 16 + half * 8;
            s8vec af[2], bfr[2];
            #pragma unroll
            for (int i = 0; i < 2; ++i)
                af[i] = *(const s8vec*)&Xs[wr * 64 + i * 32 + l31][k0];
            #pragma unroll
            for (int j = 0; j < 2; ++j)
                bfr[j] = *(const s8vec*)&Xs[wc * 64 + j * 32 + l31][k0];
            #pragma unroll
            for (int i = 0; i < 2; ++i)
                #pragma unroll
                for (int j = 0; j < 2; ++j)
                    acc[i][j] = __builtin_amdgcn_mfma_f32_32x32x16_bf16(
                        af[i], bfr[j], acc[i][j], 0, 0, 0);
        }
    }
    // channel sums: 16 consecutive lanes share one row
    #pragma unroll
    for (int i = 0; i < 4; ++i) {
        float s = rowsum[i];
        s += __shfl_down(s, 8, 16);
        s += __shfl_down(s, 4, 16);
        s += __shfl_down(s, 2, 16);
        s += __shfl_down(s, 1, 16);
        if ((lane & 15) == 0)
            atomicAdd(&sums[b * C_DIM + r0 + 64 * i], s);
    }
    float* covb = covraw + (size_t)b * C_DIM * C_DIM;
    #pragma unroll
    for (int i = 0; i < 2; ++i) {
        const int rb = wr * 64 + i * 32 + 4 * half;
        #pragma unroll
        for (int j = 0; j < 2; ++j) {
            const int cb = wc * 64 + j * 32 + l31;
            #pragma unroll
            for (int r = 0; r < 16; ++r) {
                const int row = rb + (r & 3) + 8 * (r >> 2);
                atomicAdd(&covb[row * C_DIM + cb], acc[i][j][r]);
            }
        }
    }
}

// ---------------------------------------------------------------------------
// finalize: cov = covraw/M - mu mu^T; normA = ||cov||_F; Y0 = cov/normA (bf16);
// T0 = 1.5 I - 0.5 Y0 (== Z1, since Z0 = I). Two-pass: no per-thread array.
// grid BATCH x 1024 threads.
// ---------------------------------------------------------------------------
__global__ __launch_bounds__(1024)
void finalize_cov(const float* __restrict__ covraw, const float* __restrict__ sums,
                  float* __restrict__ normA_g, unsigned short* __restrict__ Y0,
                  unsigned short* __restrict__ T0)
{
    const int b = blockIdx.x;
    const int tid = threadIdx.x;
    const float invM = 1.0f / (float)M_DIM;
    const float* cb = covraw + (size_t)b * 65536;
    const float* sb = sums + b * 256;
    float ss = 0.0f;
    #pragma unroll 4
    for (int i = 0; i < 64; ++i) {
        const int e = tid + i * 1024;
        const int r = e >> 8, c = e & 255;
        float v = cb[e] * invM - (sb[r] * invM) * (sb[c] * invM);
        ss += v * v;
    }
    __shared__ float red[16];
    __shared__ float sh_inv;
    float s = ss;
    #pragma unroll
    for (int off = 32; off; off >>= 1) s += __shfl_down(s, off, 64);
    if ((tid & 63) == 0) red[tid >> 6] = s;
    __syncthreads();
    if (tid == 0) {
        float t = 0.0f;
        #pragma unroll
        for (int i = 0; i < 16; ++i) t += red[i];
        float na = sqrtf(t);
        normA_g[b] = na;
        sh_inv = 1.0f / na;
    }
    __syncthreads();
    const float inv = sh_inv;
    unsigned short* yb = Y0 + (size_t)b * 65536;
    unsigned short* tb = T0 + (size_t)b * 65536;
    #pragma unroll 4
    for (int i = 0; i < 64; ++i) {
        const int e = tid + i * 1024;
        const int r = e >> 8, c = e & 255;
        float v = (cb[e] * invM - (sb[r] * invM) * (sb[c] * invM)) * inv;
        yb[e] = f2bf(v);
        tb[e] = f2bf(((r == c) ? 1.5f : 0.0f) - 0.5f * v);
    }
}

// ---------------------------------------------------------------------------
// NS stage: C = c0*I + c1*(A @ B). All iterates symmetric => NT-gemm.
// 64x64 tiles: grid (16, BATCH, nprod), 256 threads (2x2 waves, 32x32 each)
// ---------------------------------------------------------------------------
__global__ __launch_bounds__(256, 4)
void ns_stage(const unsigned short* __restrict__ A0, const unsigned short* __restrict__ B0,
              unsigned short* __restrict__ C0,
              const unsigned short* __restrict__ A1, const unsigned short* __restrict__ B1,
              unsigned short* __restrict__ C1,
              float c0, float c1)
{
    __shared__ unsigned short As[64][LDSP];
    __shared__ unsigned short Bs[64][LDSP];
    const int b = blockIdx.y;
    const int trow = (blockIdx.x >> 2) * 64, tcol = (blockIdx.x & 3) * 64;
    const unsigned short* A = (blockIdx.z ? A1 : A0) + (size_t)b * 65536;
    const unsigned short* B = (blockIdx.z ? B1 : B0) + (size_t)b * 65536;
    unsigned short* Cp = (blockIdx.z ? C1 : C0) + (size_t)b * 65536;

    const int tid = threadIdx.x;
    const int lane = tid & 63, wave = tid >> 6;   // 0..3
    const int wr = wave >> 1, wc = wave & 1;
    const int half = lane >> 5, l31 = lane & 31;

    f16acc acc = {};

    const int sr = tid >> 3;        // 0..31
    const int sc = (tid & 7) * 8;   // 0..56
    for (int kt = 0; kt < 4; ++kt) {
        const int kb = kt * BK;
        uint4 va[2], vb[2];
        #pragma unroll
        for (int i = 0; i < 2; ++i) {
            va[i] = *(const uint4*)(A + (size_t)(trow + sr + 32 * i) * 256 + kb + sc);
            vb[i] = *(const uint4*)(B + (size_t)(tcol + sr + 32 * i) * 256 + kb + sc);
        }
        __syncthreads();
        #pragma unroll
        for (int i = 0; i < 2; ++i) {
            *(uint4*)&As[sr + 32 * i][sc] = va[i];
            *(uint4*)&Bs[sr + 32 * i][sc] = vb[i];
        }
        __syncthreads();
        #pragma unroll
        for (int ks = 0; ks < 4; ++ks) {
            const int k0 = ks * 16 + half * 8;
            s8vec af = *(const s8vec*)&As[wr * 32 + l31][k0];
            s8vec bfr = *(const s8vec*)&Bs[wc * 32 + l31][k0];
            acc = __builtin_amdgcn_mfma_f32_32x32x16_bf16(af, bfr, acc, 0, 0, 0);
        }
    }
    const int rb = trow + wr * 32 + 4 * half;
    const int cb = tcol + wc * 32 + l31;
    #pragma unroll
    for (int r = 0; r < 16; ++r) {
        const int row = rb + (r & 3) + 8 * (r >> 2);
        float v = c1 * acc[r] + ((row == cb) ? c0 : 0.0f);
        Cp[row * 256 + cb] = f2bf(v);
    }
}

// ---------------------------------------------------------------------------
// gating: y = rowmean(Z)/sqrt(normA); h = relu(y@w1^T+b1); g = sigmoid(h@w2^T+b2)
// grid BATCH x 256 threads
// ---------------------------------------------------------------------------
__global__ __launch_bounds__(256)
void gating_kernel(const unsigned short* __restrict__ Zfin, const float* __restrict__ normA_g,
                   const float* __restrict__ w1, const float* __restrict__ b1,
                   const float* __restrict__ w2, const float* __restrict__ b2,
                   float* __restrict__ g)
{
    const int b = blockIdx.x;
    const int tid = threadIdx.x;
    __shared__ float sy[256];
    __shared__ float sh[32];
    const unsigned short* zr = Zfin + (size_t)b * 65536 + (size_t)tid * 256;
    float s = 0.0f;
    #pragma unroll
    for (int i = 0; i < 32; ++i) {
        uint4 v = *(const uint4*)(zr + i * 8);
        const unsigned short* p = (const unsigned short*)&v;
        #pragma unroll
        for (int j = 0; j < 8; ++j) s += bf2f(p[j]);
    }
    const float scale = (1.0f / 256.0f) / sqrtf(normA_g[b]);
    sy[tid] = s * scale;
    __syncthreads();
    if (tid < 32) {
        float hh = b1[tid];
        const float* w1r = w1 + tid * 256;
        for (int c = 0; c < 256; ++c) hh += w1r[c] * sy[c];
        sh[tid] = hh > 0.0f ? hh : 0.0f;
    }
    __syncthreads();
    float z = b2[tid];
    const float* w2r = w2 + tid * 32;
    #pragma unroll
    for (int j = 0; j < 32; ++j) z += w2r[j] * sh[j];
    g[b * 256 + tid] = 1.0f / (1.0f + expf(-z));
}

// ---------------------------------------------------------------------------
// scale: out = x * g[b,c]
// ---------------------------------------------------------------------------
__global__ __launch_bounds__(256)
void scale_kernel(const float* __restrict__ x, const float* __restrict__ g,
                  float* __restrict__ out)
{
    const float4* x4 = (const float4*)x;
    float4* o4 = (float4*)out;
    #pragma unroll
    for (int it = 0; it < 4; ++it) {
        size_t i = (size_t)blockIdx.x * 1024 + it * 256 + threadIdx.x;
        float gg = g[i >> 12];
        float4 v = x4[i];
        float4 r;
        r.x = v.x * gg; r.y = v.y * gg; r.z = v.z * gg; r.w = v.w * gg;
        o4[i] = r;
    }
}

extern "C" void kernel_launch(void* const* d_in, const int* in_sizes, int n_in,
                              void* d_out, int out_size, void* d_ws, size_t ws_size,
                              hipStream_t stream)
{
    const float* x  = (const float*)d_in[0];
    const float* w1 = (const float*)d_in[1];
    const float* b1 = (const float*)d_in[2];
    const float* w2 = (const float*)d_in[3];
    const float* b2 = (const float*)d_in[4];
    float* out = (float*)d_out;

    char* ws = (char*)d_ws;
    float* covraw = (float*)ws;                        // 2 MB fp32
    float* sums   = (float*)(ws + 2097152);            // 8 KB
    float* normA  = (float*)(ws + 2105344);            // 32 B
    float* g      = (float*)(ws + 2106368);            // 8 KB
    unsigned short* Ya = (unsigned short*)(ws + 4194304);
    unsigned short* Yb = (unsigned short*)(ws + 5242880);
    unsigned short* Za = (unsigned short*)(ws + 6291456);
    unsigned short* Zb = (unsigned short*)(ws + 7340032);
    unsigned short* T  = (unsigned short*)(ws + 8388608);  // total 9 MB

    hipMemsetAsync(covraw, 0, 2105344, stream);  // covraw + sums

    cov_kernel<<<dim3(KSPLIT, BATCH), 1024, 0, stream>>>(x, covraw, sums);
    // finalize: Y0 -> Ya, T0 (== Z1) -> Za. (NS iteration 0 folded: Z0=I.)
    finalize_cov<<<BATCH, 1024, 0, stream>>>(covraw, sums, normA, Ya, Za);

    // Y1 = Y0 @ T0
    ns_stage<<<dim3(16, BATCH, 1), 256, 0, stream>>>(Ya, Za, Yb, Ya, Za, Yb, 0.0f, 1.0f);

    unsigned short* Ycur = Yb; unsigned short* Yoth = Ya;
    unsigned short* Zcur = Za; unsigned short* Zoth = Zb;
    for (int it = 0; it < 4; ++it) {
        // T = 1.5 I - 0.5 * Z @ Y
        ns_stage<<<dim3(16, BATCH, 1), 256, 0, stream>>>(
            Zcur, Ycur, T, Zcur, Ycur, T, 1.5f, -0.5f);
        if (it < 3) {
            // Ynew = Y @ T ; Znew = T @ Z
            ns_stage<<<dim3(16, BATCH, 2), 256, 0, stream>>>(
                Ycur, T, Yoth, T, Zcur, Zoth, 0.0f, 1.0f);
            unsigned short* t0 = Ycur; Ycur = Yoth; Yoth = t0;
            unsigned short* t1 = Zcur; Zcur = Zoth; Zoth = t1;
        } else {
            // final iteration: only Z5 = T @ Z4 needed
            ns_stage<<<dim3(16, BATCH, 1), 256, 0, stream>>>(
                T, Zcur, Zoth, T, Zcur, Zoth, 0.0f, 1.0f);
            Zcur = Zoth;
        }
    }
    gating_kernel<<<BATCH, 256, 0, stream>>>(Zcur, normA, w1, b1, w2, b2, g);
    scale_kernel<<<8192, 256, 0, stream>>>(x, g, out);
}

// Round 3
// 388.101 us; speedup vs baseline: 1.3703x; 1.1537x over previous
//
#include <hip/hip_runtime.h>
#include <cstdint>
#include <cstddef>

typedef short s8vec __attribute__((ext_vector_type(8)));     // 8 bf16 (4 VGPRs)
typedef float f16acc __attribute__((ext_vector_type(16)));   // 16 fp32 acc

#define C_DIM 256
#define M_DIM 16384
#define BATCH 8
#define KSPLIT 32
#define KCHUNK 512
#define BK 64
#define LDSP 72   // padded LDS pitch in bf16 elems (0 bank conflicts measured)

static __device__ __forceinline__ unsigned short f2bf(float f) {
    union { float f; unsigned u; } v; v.f = f;
    unsigned r = v.u + 0x7fffu + ((v.u >> 16) & 1u);  // round-to-nearest-even
    return (unsigned short)(r >> 16);
}
static __device__ __forceinline__ float bf2f(unsigned short h) {
    union { unsigned u; float f; } v; v.u = ((unsigned)h) << 16;
    return v.f;
}

// ---------------------------------------------------------------------------
// cov partial, symmetric 3-tile: block computes one 128x128 quadrant of
// Xchunk @ Xchunk^T. tile 0:(0,0) 1:(1,1) 2:(1,0); (0,1) mirrored later.
// grid (3, KSPLIT, BATCH), 256 threads = 4 waves (2x2), 64x64 per wave.
// Diagonal tiles stage one operand (A doubles as B) and own the row sums.
// ---------------------------------------------------------------------------
__global__ __launch_bounds__(256, 2)
void cov_kernel(const float* __restrict__ x, float* __restrict__ covraw,
                float* __restrict__ sums)
{
    __shared__ unsigned short As[128][LDSP];
    __shared__ unsigned short Bs[128][LDSP];
    const int tile = blockIdx.x;                  // 0,1,2
    const int kc   = blockIdx.y;
    const int b    = blockIdx.z;
    const int trow = (tile == 0) ? 0 : 128;
    const int tcol = (tile == 2) ? 0 : trow;
    const bool diag = (tile < 2);

    const int tid  = threadIdx.x;
    const int lane = tid & 63;
    const int wave = tid >> 6;      // 0..3
    const int wr = wave >> 1, wc = wave & 1;
    const int half = lane >> 5, l31 = lane & 31;

    const float* xb = x + (size_t)b * C_DIM * M_DIM + (size_t)kc * KCHUNK;

    f16acc acc[2][2] = {};
    float rowsum[8] = {0,0,0,0,0,0,0,0};
    const int sr = tid >> 4;          // 0..15
    const int sc = (tid & 15) * 4;    // 0..60

    // prologue: load kt=0
    float4 va[8], vb[8];
    {
        const float* sa = xb + (size_t)(trow + sr) * M_DIM + sc;
        #pragma unroll
        for (int i = 0; i < 8; ++i)
            va[i] = *(const float4*)(sa + (size_t)(16 * i) * M_DIM);
        if (!diag) {
            const float* sb2 = xb + (size_t)(tcol + sr) * M_DIM + sc;
            #pragma unroll
            for (int i = 0; i < 8; ++i)
                vb[i] = *(const float4*)(sb2 + (size_t)(16 * i) * M_DIM);
        }
    }

    const unsigned short (*Bp)[LDSP] = diag ? As : Bs;

    for (int kt = 0; kt < KCHUNK / BK; ++kt) {
        __syncthreads();   // previous kt's LDS consumers done
        #pragma unroll
        for (int i = 0; i < 8; ++i) {
            if (diag) rowsum[i] += va[i].x + va[i].y + va[i].z + va[i].w;
            ushort4 p;
            p.x = f2bf(va[i].x); p.y = f2bf(va[i].y);
            p.z = f2bf(va[i].z); p.w = f2bf(va[i].w);
            *(ushort4*)&As[sr + 16 * i][sc] = p;
        }
        if (!diag) {
            #pragma unroll
            for (int i = 0; i < 8; ++i) {
                ushort4 p;
                p.x = f2bf(vb[i].x); p.y = f2bf(vb[i].y);
                p.z = f2bf(vb[i].z); p.w = f2bf(vb[i].w);
                *(ushort4*)&Bs[sr + 16 * i][sc] = p;
            }
        }
        // prefetch next tile
        if (kt < KCHUNK / BK - 1) {
            const float* sa = xb + (size_t)(trow + sr) * M_DIM + (kt + 1) * BK + sc;
            #pragma unroll
            for (int i = 0; i < 8; ++i)
                va[i] = *(const float4*)(sa + (size_t)(16 * i) * M_DIM);
            if (!diag) {
                const float* sb2 = xb + (size_t)(tcol + sr) * M_DIM + (kt + 1) * BK + sc;
                #pragma unroll
                for (int i = 0; i < 8; ++i)
                    vb[i] = *(const float4*)(sb2 + (size_t)(16 * i) * M_DIM);
            }
        }
        __syncthreads();
        #pragma unroll
        for (int ks = 0; ks < 4; ++ks) {
            const int k0 = ks * 16 + half * 8;
            s8vec af[2], bfr[2];
            #pragma unroll
            for (int i = 0; i < 2; ++i)
                af[i] = *(const s8vec*)&As[wr * 64 + i * 32 + l31][k0];
            #pragma unroll
            for (int j = 0; j < 2; ++j)
                bfr[j] = *(const s8vec*)&Bp[wc * 64 + j * 32 + l31][k0];
            #pragma unroll
            for (int i = 0; i < 2; ++i)
                #pragma unroll
                for (int j = 0; j < 2; ++j)
                    acc[i][j] = __builtin_amdgcn_mfma_f32_32x32x16_bf16(
                        af[i], bfr[j], acc[i][j], 0, 0, 0);
        }
    }
    if (diag) {
        // 16 consecutive lanes share one staged row
        #pragma unroll
        for (int i = 0; i < 8; ++i) {
            float s = rowsum[i];
            s += __shfl_down(s, 8, 16);
            s += __shfl_down(s, 4, 16);
            s += __shfl_down(s, 2, 16);
            s += __shfl_down(s, 1, 16);
            if ((lane & 15) == 0)
                atomicAdd(&sums[b * C_DIM + trow + sr + 16 * i], s);
        }
    }
    float* covb = covraw + (size_t)b * C_DIM * C_DIM;
    #pragma unroll
    for (int i = 0; i < 2; ++i) {
        const int rb = trow + wr * 64 + i * 32 + 4 * half;
        #pragma unroll
        for (int j = 0; j < 2; ++j) {
            const int cb = tcol + wc * 64 + j * 32 + l31;
            #pragma unroll
            for (int r = 0; r < 16; ++r) {
                const int row = rb + (r & 3) + 8 * (r >> 2);
                atomicAdd(&covb[row * C_DIM + cb], acc[i][j][r]);
            }
        }
    }
}

// ---------------------------------------------------------------------------
// normsq: ssq[b] = sum (cov_ij)^2 with cov = covraw/M - mu mu^T, reading the
// (0,1) quadrant from its (1,0) mirror. grid (8 slabs, BATCH) x 256.
// ---------------------------------------------------------------------------
__global__ __launch_bounds__(256)
void cov_normsq(const float* __restrict__ covraw, const float* __restrict__ sums,
                float* __restrict__ normsq)
{
    const int slab = blockIdx.x;   // 32 rows each
    const int b    = blockIdx.y;
    const int tid  = threadIdx.x;
    const float invM = 1.0f / (float)M_DIM;
    const float* cb = covraw + (size_t)b * 65536;
    const float* sb = sums + b * 256;
    float ss = 0.0f;
    #pragma unroll 4
    for (int i = 0; i < 32; ++i) {
        const int e = slab * 8192 + i * 256 + tid;
        const int r = e >> 8, c = e & 255;
        const float raw = (r < 128 && c >= 128) ? cb[c * 256 + r] : cb[e];
        const float v = raw * invM - (sb[r] * invM) * (sb[c] * invM);
        ss += v * v;
    }
    #pragma unroll
    for (int off = 32; off; off >>= 1) ss += __shfl_down(ss, off, 64);
    __shared__ float red[4];
    if ((tid & 63) == 0) red[tid >> 6] = ss;
    __syncthreads();
    if (tid == 0)
        atomicAdd(&normsq[b], red[0] + red[1] + red[2] + red[3]);
}

// ---------------------------------------------------------------------------
// emit: Y0 = cov/normA (bf16), T0 = 1.5 I - 0.5 Y0 (== Z1 since Z0=I).
// grid (8 slabs, BATCH) x 256.
// ---------------------------------------------------------------------------
__global__ __launch_bounds__(256)
void emit_YT(const float* __restrict__ covraw, const float* __restrict__ sums,
             const float* __restrict__ normsq, float* __restrict__ normA_g,
             unsigned short* __restrict__ Y0, unsigned short* __restrict__ T0)
{
    const int slab = blockIdx.x;
    const int b    = blockIdx.y;
    const int tid  = threadIdx.x;
    const float invM = 1.0f / (float)M_DIM;
    const float nq  = normsq[b];
    const float inv = rsqrtf(nq);
    if (slab == 0 && tid == 0) normA_g[b] = sqrtf(nq);
    const float* cb = covraw + (size_t)b * 65536;
    const float* sb = sums + b * 256;
    unsigned short* yb = Y0 + (size_t)b * 65536;
    unsigned short* tb = T0 + (size_t)b * 65536;
    #pragma unroll 4
    for (int i = 0; i < 32; ++i) {
        const int e = slab * 8192 + i * 256 + tid;
        const int r = e >> 8, c = e & 255;
        const float raw = (r < 128 && c >= 128) ? cb[c * 256 + r] : cb[e];
        const float v = (raw * invM - (sb[r] * invM) * (sb[c] * invM)) * inv;
        yb[e] = f2bf(v);
        tb[e] = f2bf(((r == c) ? 1.5f : 0.0f) - 0.5f * v);
    }
}

// ---------------------------------------------------------------------------
// NS stage: C = c0*I + c1*(A @ B). All iterates symmetric => NT-gemm.
// 64x64 tiles: grid (16, BATCH, nprod), 256 threads (2x2 waves, 32x32 each)
// ---------------------------------------------------------------------------
__global__ __launch_bounds__(256, 4)
void ns_stage(const unsigned short* __restrict__ A0, const unsigned short* __restrict__ B0,
              unsigned short* __restrict__ C0,
              const unsigned short* __restrict__ A1, const unsigned short* __restrict__ B1,
              unsigned short* __restrict__ C1,
              float c0, float c1)
{
    __shared__ unsigned short As[64][LDSP];
    __shared__ unsigned short Bs[64][LDSP];
    const int b = blockIdx.y;
    const int trow = (blockIdx.x >> 2) * 64, tcol = (blockIdx.x & 3) * 64;
    const unsigned short* A = (blockIdx.z ? A1 : A0) + (size_t)b * 65536;
    const unsigned short* B = (blockIdx.z ? B1 : B0) + (size_t)b * 65536;
    unsigned short* Cp = (blockIdx.z ? C1 : C0) + (size_t)b * 65536;

    const int tid = threadIdx.x;
    const int lane = tid & 63, wave = tid >> 6;   // 0..3
    const int wr = wave >> 1, wc = wave & 1;
    const int half = lane >> 5, l31 = lane & 31;

    f16acc acc = {};

    const int sr = tid >> 3;        // 0..31
    const int sc = (tid & 7) * 8;   // 0..56
    for (int kt = 0; kt < 4; ++kt) {
        const int kb = kt * BK;
        uint4 va[2], vb[2];
        #pragma unroll
        for (int i = 0; i < 2; ++i) {
            va[i] = *(const uint4*)(A + (size_t)(trow + sr + 32 * i) * 256 + kb + sc);
            vb[i] = *(const uint4*)(B + (size_t)(tcol + sr + 32 * i) * 256 + kb + sc);
        }
        __syncthreads();
        #pragma unroll
        for (int i = 0; i < 2; ++i) {
            *(uint4*)&As[sr + 32 * i][sc] = va[i];
            *(uint4*)&Bs[sr + 32 * i][sc] = vb[i];
        }
        __syncthreads();
        #pragma unroll
        for (int ks = 0; ks < 4; ++ks) {
            const int k0 = ks * 16 + half * 8;
            s8vec af = *(const s8vec*)&As[wr * 32 + l31][k0];
            s8vec bfr = *(const s8vec*)&Bs[wc * 32 + l31][k0];
            acc = __builtin_amdgcn_mfma_f32_32x32x16_bf16(af, bfr, acc, 0, 0, 0);
        }
    }
    const int rb = trow + wr * 32 + 4 * half;
    const int cb = tcol + wc * 32 + l31;
    #pragma unroll
    for (int r = 0; r < 16; ++r) {
        const int row = rb + (r & 3) + 8 * (r >> 2);
        float v = c1 * acc[r] + ((row == cb) ? c0 : 0.0f);
        Cp[row * 256 + cb] = f2bf(v);
    }
}

// ---------------------------------------------------------------------------
// gating: y = rowmean(Z)/sqrt(normA); h = relu(y@w1^T+b1); g = sigmoid(h@w2^T+b2)
// ---------------------------------------------------------------------------
__global__ __launch_bounds__(256)
void gating_kernel(const unsigned short* __restrict__ Zfin, const float* __restrict__ normA_g,
                   const float* __restrict__ w1, const float* __restrict__ b1,
                   const float* __restrict__ w2, const float* __restrict__ b2,
                   float* __restrict__ g)
{
    const int b = blockIdx.x;
    const int tid = threadIdx.x;
    __shared__ float sy[256];
    __shared__ float sh[32];
    const unsigned short* zr = Zfin + (size_t)b * 65536 + (size_t)tid * 256;
    float s = 0.0f;
    #pragma unroll
    for (int i = 0; i < 32; ++i) {
        uint4 v = *(const uint4*)(zr + i * 8);
        const unsigned short* p = (const unsigned short*)&v;
        #pragma unroll
        for (int j = 0; j < 8; ++j) s += bf2f(p[j]);
    }
    const float scale = (1.0f / 256.0f) / sqrtf(normA_g[b]);
    sy[tid] = s * scale;
    __syncthreads();
    if (tid < 32) {
        float hh = b1[tid];
        const float* w1r = w1 + tid * 256;
        for (int c = 0; c < 256; ++c) hh += w1r[c] * sy[c];
        sh[tid] = hh > 0.0f ? hh : 0.0f;
    }
    __syncthreads();
    float z = b2[tid];
    const float* w2r = w2 + tid * 32;
    #pragma unroll
    for (int j = 0; j < 32; ++j) z += w2r[j] * sh[j];
    g[b * 256 + tid] = 1.0f / (1.0f + expf(-z));
}

// ---------------------------------------------------------------------------
// scale: out = x * g[b,c]
// ---------------------------------------------------------------------------
__global__ __launch_bounds__(256)
void scale_kernel(const float* __restrict__ x, const float* __restrict__ g,
                  float* __restrict__ out)
{
    const float4* x4 = (const float4*)x;
    float4* o4 = (float4*)out;
    #pragma unroll
    for (int it = 0; it < 4; ++it) {
        size_t i = (size_t)blockIdx.x * 1024 + it * 256 + threadIdx.x;
        float gg = g[i >> 12];
        float4 v = x4[i];
        float4 r;
        r.x = v.x * gg; r.y = v.y * gg; r.z = v.z * gg; r.w = v.w * gg;
        o4[i] = r;
    }
}

extern "C" void kernel_launch(void* const* d_in, const int* in_sizes, int n_in,
                              void* d_out, int out_size, void* d_ws, size_t ws_size,
                              hipStream_t stream)
{
    const float* x  = (const float*)d_in[0];
    const float* w1 = (const float*)d_in[1];
    const float* b1 = (const float*)d_in[2];
    const float* w2 = (const float*)d_in[3];
    const float* b2 = (const float*)d_in[4];
    float* out = (float*)d_out;

    char* ws = (char*)d_ws;
    float* covraw = (float*)ws;                        // 2 MB fp32
    float* sums   = (float*)(ws + 2097152);            // 8 KB
    float* normsq = (float*)(ws + 2105344);            // 32 B
    float* normA  = (float*)(ws + 2105600);            // 32 B
    float* g      = (float*)(ws + 2106368);            // 8 KB
    unsigned short* Ya = (unsigned short*)(ws + 4194304);
    unsigned short* Yb = (unsigned short*)(ws + 5242880);
    unsigned short* Za = (unsigned short*)(ws + 6291456);
    unsigned short* Zb = (unsigned short*)(ws + 7340032);
    unsigned short* T  = (unsigned short*)(ws + 8388608);  // 1 MB, total 9.44 MB

    hipMemsetAsync(covraw, 0, 2105408, stream);  // covraw + sums + normsq

    cov_kernel<<<dim3(3, KSPLIT, BATCH), 256, 0, stream>>>(x, covraw, sums);
    cov_normsq<<<dim3(8, BATCH), 256, 0, stream>>>(covraw, sums, normsq);
    // Y0 -> Ya, T0 (== Z1) -> Za. (NS iteration 0 folded: Z0=I.)
    emit_YT<<<dim3(8, BATCH), 256, 0, stream>>>(covraw, sums, normsq, normA, Ya, Za);

    // Y1 = Y0 @ T0
    ns_stage<<<dim3(16, BATCH, 1), 256, 0, stream>>>(Ya, Za, Yb, Ya, Za, Yb, 0.0f, 1.0f);

    unsigned short* Ycur = Yb; unsigned short* Yoth = Ya;
    unsigned short* Zcur = Za; unsigned short* Zoth = Zb;
    for (int it = 0; it < 4; ++it) {
        // T = 1.5 I - 0.5 * Z @ Y
        ns_stage<<<dim3(16, BATCH, 1), 256, 0, stream>>>(
            Zcur, Ycur, T, Zcur, Ycur, T, 1.5f, -0.5f);
        if (it < 3) {
            // Ynew = Y @ T ; Znew = T @ Z
            ns_stage<<<dim3(16, BATCH, 2), 256, 0, stream>>>(
                Ycur, T, Yoth, T, Zcur, Zoth, 0.0f, 1.0f);
            unsigned short* t0 = Ycur; Ycur = Yoth; Yoth = t0;
            unsigned short* t1 = Zcur; Zcur = Zoth; Zoth = t1;
        } else {
            // final iteration: only Z5 = T @ Z4 needed
            ns_stage<<<dim3(16, BATCH, 1), 256, 0, stream>>>(
                T, Zcur, Zoth, T, Zcur, Zoth, 0.0f, 1.0f);
            Zcur = Zoth;
        }
    }
    gating_kernel<<<BATCH, 256, 0, stream>>>(Zcur, normA, w1, b1, w2, b2, g);
    scale_kernel<<<8192, 256, 0, stream>>>(x, g, out);
}